// Round 2
// baseline (368.127 us; speedup 1.0000x reference)
//
#include <hip/hip_runtime.h>
#include <math.h>

#define C_DIM 512
#define K_DIM 64
#define N_PIX 784
#define B_DIM 128
#define M_ROWS (B_DIM * N_PIX)   // 100352
#define CC 32                     // C-chunk
#define MT 128                    // rows per block

// exp(20*d - 20) = exp2(KA*d + KB)
#define KA 28.853900817779268f
#define KB (-28.853900817779268f)

// ---------------- Kernel A: normalize anchors (64 blocks x 64 threads) ----------------
__global__ __launch_bounds__(64) void anchors_norm_kernel(const float* __restrict__ a,
                                                          float* __restrict__ an) {
    const int k = blockIdx.x;
    const int l = threadIdx.x;  // 0..63
    const float4* ap = (const float4*)(a + (size_t)k * C_DIM);
    float4 v0 = ap[l];
    float4 v1 = ap[l + 64];
    float ss = v0.x * v0.x + v0.y * v0.y + v0.z * v0.z + v0.w * v0.w +
               v1.x * v1.x + v1.y * v1.y + v1.z * v1.z + v1.w * v1.w;
#pragma unroll
    for (int m = 1; m < 64; m <<= 1) ss += __shfl_xor(ss, m);
    const float rn = 1.0f / (sqrtf(ss) + 1e-12f);
    float4* anp = (float4*)(an + (size_t)k * C_DIM);
    v0.x *= rn; v0.y *= rn; v0.z *= rn; v0.w *= rn;
    v1.x *= rn; v1.y *= rn; v1.z *= rn; v1.w *= rn;
    anp[l] = v0;
    anp[l + 64] = v1;
}

// ---------------- Kernel B: cosine GEMM + T ----------------
// 784 blocks x 256 threads; block tile 128 rows x 64 anchors; thread tile 8x4.
// LDS XOR-swizzle: element (c,r) at word c*128 + (((r>>2)^((c>>2)&7))<<2 | (r&3)).
// Write banks exactly 2-way (free); reads are aligned ds_read_b128, conflict-free.
__global__ __launch_bounds__(256) void cost_t_kernel(const float* __restrict__ x,
                                                     const float* __restrict__ an,
                                                     float* __restrict__ Tg) {
    __shared__ __align__(16) float xs[CC * MT];     // 16 KB, swizzled
    __shared__ __align__(16) float as[CC * K_DIM];  // 8 KB, swizzled
    __shared__ float nrm[MT];

    const int tid = threadIdx.x;
    const int m0 = blockIdx.x * MT;
    const int tk = tid & 15;   // anchors tk*4..+3
    const int tm = tid >> 4;   // rows tm*8..+7

    // staging coords
    const int xr = tid >> 3;        // 0..31 (+32q)
    const int xc = (tid & 7) * 4;   // 0..28
    const int ar = tid >> 2;        // 0..63
    const int ac = (tid & 3) * 4;   // 0..12 (+16h)

    const float* xbase = x + (size_t)m0 * C_DIM;

    float acc[8][4] = {};
    float ss[4] = {0.f, 0.f, 0.f, 0.f};

    float4 px[4], pa[2];
    // preload chunk 0
#pragma unroll
    for (int q = 0; q < 4; ++q)
        px[q] = *(const float4*)(xbase + (size_t)(xr + 32 * q) * C_DIM + xc);
    pa[0] = *(const float4*)(an + (size_t)ar * C_DIM + ac);
    pa[1] = *(const float4*)(an + (size_t)ar * C_DIM + 16 + ac);

    for (int ch = 0; ch < C_DIM / CC; ++ch) {
        __syncthreads();  // previous chunk's LDS reads complete
#pragma unroll
        for (int q = 0; q < 4; ++q) {
            const int r = xr + 32 * q;
            const float v[4] = {px[q].x, px[q].y, px[q].z, px[q].w};
#pragma unroll
            for (int i = 0; i < 4; ++i) {
                const int c = xc + i;
                xs[c * MT + ((((r >> 2) ^ ((c >> 2) & 7)) << 2) | (r & 3))] = v[i];
            }
            ss[q] += v[0] * v[0] + v[1] * v[1] + v[2] * v[2] + v[3] * v[3];
        }
#pragma unroll
        for (int h = 0; h < 2; ++h) {
            const float v[4] = {pa[h].x, pa[h].y, pa[h].z, pa[h].w};
#pragma unroll
            for (int i = 0; i < 4; ++i) {
                const int c = ac + 16 * h + i;
                as[c * K_DIM + ((((ar >> 2) ^ ((c >> 2) & 7)) << 2) | (ar & 3))] = v[i];
            }
        }
        __syncthreads();

        // prefetch next chunk (no wait until next write phase -> overlaps compute)
        if (ch + 1 < C_DIM / CC) {
            const int c0 = (ch + 1) * CC;
#pragma unroll
            for (int q = 0; q < 4; ++q)
                px[q] = *(const float4*)(xbase + (size_t)(xr + 32 * q) * C_DIM + c0 + xc);
            pa[0] = *(const float4*)(an + (size_t)ar * C_DIM + c0 + ac);
            pa[1] = *(const float4*)(an + (size_t)ar * C_DIM + c0 + 16 + ac);
        }

        const float4* xs4 = (const float4*)xs;
        const float4* as4 = (const float4*)as;
#pragma unroll
        for (int c = 0; c < CC; ++c) {
            const int s = (c >> 2) & 7;
            const float4 xv0 = xs4[c * (MT / 4) + ((tm * 2) ^ s)];      // rows tm*8..+3
            const float4 xv1 = xs4[c * (MT / 4) + ((tm * 2 + 1) ^ s)];  // rows tm*8+4..+7
            const float4 av = as4[c * (K_DIM / 4) + (tk ^ s)];          // anchors tk*4..+3
            acc[0][0] += xv0.x * av.x; acc[0][1] += xv0.x * av.y; acc[0][2] += xv0.x * av.z; acc[0][3] += xv0.x * av.w;
            acc[1][0] += xv0.y * av.x; acc[1][1] += xv0.y * av.y; acc[1][2] += xv0.y * av.z; acc[1][3] += xv0.y * av.w;
            acc[2][0] += xv0.z * av.x; acc[2][1] += xv0.z * av.y; acc[2][2] += xv0.z * av.z; acc[2][3] += xv0.z * av.w;
            acc[3][0] += xv0.w * av.x; acc[3][1] += xv0.w * av.y; acc[3][2] += xv0.w * av.z; acc[3][3] += xv0.w * av.w;
            acc[4][0] += xv1.x * av.x; acc[4][1] += xv1.x * av.y; acc[4][2] += xv1.x * av.z; acc[4][3] += xv1.x * av.w;
            acc[5][0] += xv1.y * av.x; acc[5][1] += xv1.y * av.y; acc[5][2] += xv1.y * av.z; acc[5][3] += xv1.y * av.w;
            acc[6][0] += xv1.z * av.x; acc[6][1] += xv1.z * av.y; acc[6][2] += xv1.z * av.z; acc[6][3] += xv1.z * av.w;
            acc[7][0] += xv1.w * av.x; acc[7][1] += xv1.w * av.y; acc[7][2] += xv1.w * av.z; acc[7][3] += xv1.w * av.w;
        }
    }

    // row inverse norms: reduce sumsq over the 8 lanes (bits 0..2) sharing a row
#pragma unroll
    for (int q = 0; q < 4; ++q) {
        float v = ss[q];
        v += __shfl_xor(v, 1); v += __shfl_xor(v, 2); v += __shfl_xor(v, 4);
        if ((tid & 7) == 0) nrm[xr + 32 * q] = 1.0f / (sqrtf(v) + 1e-12f);
    }
    __syncthreads();

#pragma unroll
    for (int i = 0; i < 8; ++i) {
        const float rn = nrm[tm * 8 + i];
        float t = exp2f(KA * (acc[i][0] * rn) + KB) + exp2f(KA * (acc[i][1] * rn) + KB) +
                  exp2f(KA * (acc[i][2] * rn) + KB) + exp2f(KA * (acc[i][3] * rn) + KB);
        t += __shfl_xor(t, 1); t += __shfl_xor(t, 2);
        t += __shfl_xor(t, 4); t += __shfl_xor(t, 8);
        if (tk == 0) Tg[m0 + tm * 8 + i] = t;
    }
}

// ---------------- Kernel C: Sinkhorn scalar recurrence, in-place coef ----------------
// w_{t+1} = w_t * (mu*N) / sum_n (w T)/(1+w T);  coef = (2/N) * wT/(1+wT)
__global__ __launch_bounds__(256) void sinkhorn_kernel(float* __restrict__ Tc) {
    const int b = blockIdx.x;
    const int tid = threadIdx.x;
    __shared__ float wsum[4];
    __shared__ float wsh;
    float r[4];
#pragma unroll
    for (int q = 0; q < 4; ++q) {
        const int n = tid + q * 256;
        r[q] = (n < N_PIX) ? Tc[b * N_PIX + n] : 0.f;
    }
    float w = 1.0f;
    for (int it = 0; it < 10; ++it) {
        float p = 0.f;
#pragma unroll
        for (int q = 0; q < 4; ++q) {
            const float wr = w * r[q];
            p += wr / (1.0f + wr);
        }
#pragma unroll
        for (int m = 1; m < 64; m <<= 1) p += __shfl_xor(p, m);
        if ((tid & 63) == 0) wsum[tid >> 6] = p;
        __syncthreads();
        if (tid == 0) {
            const float s = wsum[0] + wsum[1] + wsum[2] + wsum[3];
            wsh = w * 392.0f / s;  // mu*N = 0.5*784
        }
        __syncthreads();
        w = wsh;
    }
    const float scale = 2.0f / 784.0f;
#pragma unroll
    for (int q = 0; q < 4; ++q) {
        const int n = tid + q * 256;
        if (n < N_PIX) {
            const float wr = w * r[q];
            Tc[b * N_PIX + n] = scale * wr / (1.0f + wr);
        }
    }
}

// ---------------- Kernel D: weighted pooling ----------------
// grid = 128 batches x 8 n-chunks; out pre-zeroed. float4 loads, 2 rows in flight.
__global__ __launch_bounds__(256) void pool_kernel(const float* __restrict__ x,
                                                   const float* __restrict__ coef,
                                                   float* __restrict__ out) {
    const int bid = blockIdx.x;
    const int b = bid >> 3;
    const int n0 = (bid & 7) * 98;  // 8*98 = 784
    const int half = threadIdx.x >> 7;       // 0/1
    const int c4 = (threadIdx.x & 127) * 4;  // channel float4
    const float* xb = x + (size_t)b * N_PIX * C_DIM + c4;
    const float* cf = coef + b * N_PIX + n0 + half;
    float4 acc = {0.f, 0.f, 0.f, 0.f};
#pragma unroll 7
    for (int it = 0; it < 49; ++it) {
        const int n = n0 + it * 2 + half;
        const float a = cf[it * 2];  // wave-uniform -> scalar load
        const float4 xv = *(const float4*)(xb + (size_t)n * C_DIM);
        acc.x += a * xv.x; acc.y += a * xv.y; acc.z += a * xv.z; acc.w += a * xv.w;
    }
    float* o = out + b * C_DIM + c4;
    atomicAdd(o + 0, acc.x);
    atomicAdd(o + 1, acc.y);
    atomicAdd(o + 2, acc.z);
    atomicAdd(o + 3, acc.w);
}

extern "C" void kernel_launch(void* const* d_in, const int* in_sizes, int n_in,
                              void* d_out, int out_size, void* d_ws, size_t ws_size,
                              hipStream_t stream) {
    const float* x = (const float*)d_in[0];       // (128,28,28,512) fp32
    const float* anchors = (const float*)d_in[1]; // (64,512) fp32
    float* out = (float*)d_out;                   // (128,512) fp32

    float* an = (float*)d_ws;                          // 64*512 floats
    float* Tc = (float*)d_ws + (size_t)K_DIM * C_DIM;  // 128*784 floats (T, then coef)

    anchors_norm_kernel<<<K_DIM, 64, 0, stream>>>(anchors, an);
    cost_t_kernel<<<M_ROWS / MT, 256, 0, stream>>>(x, an, Tc);
    sinkhorn_kernel<<<B_DIM, 256, 0, stream>>>(Tc);
    hipMemsetAsync(d_out, 0, (size_t)out_size * sizeof(float), stream);
    pool_kernel<<<B_DIM * 8, 256, 0, stream>>>(x, Tc, out);
}

// Round 3
// 334.459 us; speedup vs baseline: 1.1007x; 1.1007x over previous
//
#include <hip/hip_runtime.h>
#include <math.h>

#define C_DIM 512
#define K_DIM 64
#define N_PIX 784
#define B_DIM 128
#define M_ROWS (B_DIM * N_PIX)   // 100352
#define MT 128                    // rows per block tile
#define KC 32                     // K chunk (one 16x16x32 K-step)
#define XS 40                     // LDS row stride in ushorts (32 + 8 pad; 80 B, 16B-aligned)
#define NCH (C_DIM / KC)          // 16 chunks

// exp(20*d - 20) = exp2(KA*d + KB)
#define KA 28.853900817779268f
#define KB (-28.853900817779268f)

typedef __attribute__((ext_vector_type(8))) short short8;            // MFMA A/B frag (8 bf16)
typedef __attribute__((ext_vector_type(4))) float f32x4;             // MFMA C/D frag
typedef __attribute__((ext_vector_type(8))) unsigned short ushort8;  // 16B staging

static __device__ __forceinline__ unsigned short f2bf(float f) {
    unsigned u = __builtin_bit_cast(unsigned, f);
    u += 0x7fff + ((u >> 16) & 1);  // round-to-nearest-even
    return (unsigned short)(u >> 16);
}
static __device__ __forceinline__ float bf2f(unsigned short h) {
    unsigned u = ((unsigned)h) << 16;
    return __builtin_bit_cast(float, u);
}

// ---------------- Kernel A: normalize anchors -> bf16 hi/lo (64 blocks x 64 threads) --------
__global__ __launch_bounds__(64) void anchors_norm_kernel(const float* __restrict__ a,
                                                          unsigned short* __restrict__ an_h,
                                                          unsigned short* __restrict__ an_l) {
    const int k = blockIdx.x;
    const int l = threadIdx.x;  // 0..63
    const float4* ap = (const float4*)(a + (size_t)k * C_DIM);
    float4 v0 = ap[l];
    float4 v1 = ap[l + 64];
    float ss = v0.x * v0.x + v0.y * v0.y + v0.z * v0.z + v0.w * v0.w +
               v1.x * v1.x + v1.y * v1.y + v1.z * v1.z + v1.w * v1.w;
#pragma unroll
    for (int m = 1; m < 64; m <<= 1) ss += __shfl_xor(ss, m);
    const float rn = 1.0f / (sqrtf(ss) + 1e-12f);
    const float vv[8] = {v0.x * rn, v0.y * rn, v0.z * rn, v0.w * rn,
                         v1.x * rn, v1.y * rn, v1.z * rn, v1.w * rn};
    ushort8 H, L;
#pragma unroll
    for (int i = 0; i < 8; ++i) {
        const unsigned short h = f2bf(vv[i]);
        H[i] = h;
        L[i] = f2bf(vv[i] - bf2f(h));
    }
    // elements 0..3 -> col l*4 ; elements 4..7 -> col 256 + l*4
    unsigned short* ph = an_h + (size_t)k * C_DIM;
    unsigned short* pl = an_l + (size_t)k * C_DIM;
    *(uint2*)(ph + l * 4) = *(uint2*)&H;              // low 4 ushorts
    *(uint2*)(ph + 256 + l * 4) = *((uint2*)&H + 1);  // high 4 ushorts
    *(uint2*)(pl + l * 4) = *(uint2*)&L;
    *(uint2*)(pl + 256 + l * 4) = *((uint2*)&L + 1);
}

// ---------------- Kernel B: cosine GEMM via bf16 hi/lo MFMA + T ----------------
// 784 blocks x 256 threads (4 waves). Block tile 128 rows x 64 anchors.
// Wave w owns rows w*32..+31 (2 row-tiles of 16) x 4 col-tiles of 16.
// A-frag: lane holds A[m=lane&15][k=(lane>>4)*8+j]; B-frag symmetric (anchors row-major).
// C/D: col(anchor)=lane&15, row=(lane>>4)*4+reg.
__global__ __launch_bounds__(256) void cost_t_kernel(const float* __restrict__ x,
                                                     const unsigned short* __restrict__ an_h,
                                                     const unsigned short* __restrict__ an_l,
                                                     float* __restrict__ Tg) {
    __shared__ __align__(16) unsigned short xh[MT * XS];     // 10240 B
    __shared__ __align__(16) unsigned short xl[MT * XS];     // 10240 B
    __shared__ __align__(16) unsigned short ah[K_DIM * XS];  // 5120 B
    __shared__ __align__(16) unsigned short al[K_DIM * XS];  // 5120 B
    __shared__ float nrm[MT];

    const int tid = threadIdx.x;
    const int m0 = blockIdx.x * MT;
    const int w = tid >> 6;   // wave 0..3
    const int l = tid & 63;   // lane

    // x staging: thread -> row xr (0..127), half hf (cols hf*16..+15 of the chunk)
    const int xr = tid >> 1;
    const int hf = tid & 1;
    // anchor staging: thread -> row ar (0..63), cols aq*8..+7
    const int ar = tid >> 2;
    const int aq = tid & 3;

    const float* xrow = x + (size_t)(m0 + xr) * C_DIM + hf * 16;
    const unsigned short* arow_h = an_h + (size_t)ar * C_DIM + aq * 8;
    const unsigned short* arow_l = an_l + (size_t)ar * C_DIM + aq * 8;

    f32x4 acc[2][4];
#pragma unroll
    for (int rt = 0; rt < 2; ++rt)
#pragma unroll
        for (int ct = 0; ct < 4; ++ct) acc[rt][ct] = (f32x4){0.f, 0.f, 0.f, 0.f};
    float ss = 0.f;

    float4 px[4];
    ushort8 pah, pal;
#pragma unroll
    for (int i = 0; i < 4; ++i) px[i] = *(const float4*)(xrow + i * 4);
    pah = *(const ushort8*)arow_h;
    pal = *(const ushort8*)arow_l;

    for (int ch = 0; ch < NCH; ++ch) {
        __syncthreads();  // previous chunk's LDS reads complete
        // convert + stage x (16 floats -> hi/lo bf16)
        ushort8 H0, H1, L0, L1;
#pragma unroll
        for (int i = 0; i < 4; ++i) {
            const float vv[4] = {px[i].x, px[i].y, px[i].z, px[i].w};
#pragma unroll
            for (int j = 0; j < 4; ++j) {
                const float v = vv[j];
                ss += v * v;
                const unsigned short h = f2bf(v);
                const unsigned short lo = f2bf(v - bf2f(h));
                const int idx = i * 4 + j;
                if (idx < 8) { H0[idx] = h; L0[idx] = lo; }
                else         { H1[idx - 8] = h; L1[idx - 8] = lo; }
            }
        }
        *(ushort8*)&xh[xr * XS + hf * 16] = H0;
        *(ushort8*)&xh[xr * XS + hf * 16 + 8] = H1;
        *(ushort8*)&xl[xr * XS + hf * 16] = L0;
        *(ushort8*)&xl[xr * XS + hf * 16 + 8] = L1;
        *(ushort8*)&ah[ar * XS + aq * 8] = pah;
        *(ushort8*)&al[ar * XS + aq * 8] = pal;
        __syncthreads();

        // prefetch next chunk (overlaps MFMA below)
        if (ch + 1 < NCH) {
            const int c0 = (ch + 1) * KC;
#pragma unroll
            for (int i = 0; i < 4; ++i) px[i] = *(const float4*)(xrow + c0 + i * 4);
            pah = *(const ushort8*)(arow_h + c0);
            pal = *(const ushort8*)(arow_l + c0);
        }

        // MFMA: one K-step of 32
        const int fr = l & 15;
        const int ko = (l >> 4) << 3;
        short8 axh[2], axl[2];
#pragma unroll
        for (int rt = 0; rt < 2; ++rt) {
            const int row = w * 32 + rt * 16 + fr;
            axh[rt] = *(const short8*)&xh[row * XS + ko];
            axl[rt] = *(const short8*)&xl[row * XS + ko];
        }
#pragma unroll
        for (int ct = 0; ct < 4; ++ct) {
            const int arw = ct * 16 + fr;
            const short8 bh = *(const short8*)&ah[arw * XS + ko];
            const short8 bl = *(const short8*)&al[arw * XS + ko];
#pragma unroll
            for (int rt = 0; rt < 2; ++rt) {
                acc[rt][ct] = __builtin_amdgcn_mfma_f32_16x16x32_bf16(axh[rt], bh, acc[rt][ct], 0, 0, 0);
                acc[rt][ct] = __builtin_amdgcn_mfma_f32_16x16x32_bf16(axl[rt], bh, acc[rt][ct], 0, 0, 0);
                acc[rt][ct] = __builtin_amdgcn_mfma_f32_16x16x32_bf16(axh[rt], bl, acc[rt][ct], 0, 0, 0);
            }
        }
    }

    // row inverse norms: lane pair (bit0) shares a row
    ss += __shfl_xor(ss, 1);
    if ((tid & 1) == 0) nrm[xr] = 1.0f / (sqrtf(ss) + 1e-12f);
    __syncthreads();

    // epilogue: T[m] = sum_k exp(20*cos - 20)
#pragma unroll
    for (int rt = 0; rt < 2; ++rt) {
#pragma unroll
        for (int i = 0; i < 4; ++i) {
            const int m = w * 32 + rt * 16 + ((l >> 4) << 2) + i;
            const float rn = nrm[m];
            float t = exp2f(KA * (acc[rt][0][i] * rn) + KB) +
                      exp2f(KA * (acc[rt][1][i] * rn) + KB) +
                      exp2f(KA * (acc[rt][2][i] * rn) + KB) +
                      exp2f(KA * (acc[rt][3][i] * rn) + KB);
            t += __shfl_xor(t, 1); t += __shfl_xor(t, 2);
            t += __shfl_xor(t, 4); t += __shfl_xor(t, 8);
            if ((l & 15) == 0) Tg[m0 + m] = t;
        }
    }
}

// ---------------- Kernel C: Sinkhorn scalar recurrence, in-place coef ----------------
// w_{t+1} = w_t * (mu*N) / sum_n (w T)/(1+w T);  coef = (2/N) * wT/(1+wT)
__global__ __launch_bounds__(256) void sinkhorn_kernel(float* __restrict__ Tc) {
    const int b = blockIdx.x;
    const int tid = threadIdx.x;
    __shared__ float wsum[4];
    __shared__ float wsh;
    float r[4];
#pragma unroll
    for (int q = 0; q < 4; ++q) {
        const int n = tid + q * 256;
        r[q] = (n < N_PIX) ? Tc[b * N_PIX + n] : 0.f;
    }
    float w = 1.0f;
    for (int it = 0; it < 10; ++it) {
        float p = 0.f;
#pragma unroll
        for (int q = 0; q < 4; ++q) {
            const float wr = w * r[q];
            p += wr / (1.0f + wr);
        }
#pragma unroll
        for (int m = 1; m < 64; m <<= 1) p += __shfl_xor(p, m);
        if ((tid & 63) == 0) wsum[tid >> 6] = p;
        __syncthreads();
        if (tid == 0) {
            const float s = wsum[0] + wsum[1] + wsum[2] + wsum[3];
            wsh = w * 392.0f / s;  // mu*N = 0.5*784
        }
        __syncthreads();
        w = wsh;
    }
    const float scale = 2.0f / 784.0f;
#pragma unroll
    for (int q = 0; q < 4; ++q) {
        const int n = tid + q * 256;
        if (n < N_PIX) {
            const float wr = w * r[q];
            Tc[b * N_PIX + n] = scale * wr / (1.0f + wr);
        }
    }
}

// ---------------- Kernel D: weighted pooling, no atomics ----------------
// 512 blocks = (batch, quarter of 196 rows); partials to ws, then reduce.
__global__ __launch_bounds__(256) void pool_partial(const float* __restrict__ x,
                                                    const float* __restrict__ coef,
                                                    float* __restrict__ part) {
    const int bid = blockIdx.x;
    const int b = bid >> 2;
    const int n0 = (bid & 3) * 196;
    const int c2 = threadIdx.x * 2;
    const float* xb = x + (size_t)b * N_PIX * C_DIM + (size_t)n0 * C_DIM + c2;
    const float* cf = coef + b * N_PIX + n0;
    float2 acc = {0.f, 0.f};
#pragma unroll 4
    for (int i = 0; i < 196; ++i) {
        const float a = cf[i];  // uniform across block -> scalar load
        const float2 xv = *(const float2*)(xb + (size_t)i * C_DIM);
        acc.x += a * xv.x;
        acc.y += a * xv.y;
    }
    *(float2*)(part + (size_t)bid * C_DIM + c2) = acc;
}

__global__ __launch_bounds__(256) void pool_reduce(const float* __restrict__ part,
                                                   float* __restrict__ out) {
    const int i = blockIdx.x * 256 + threadIdx.x;  // over b*512 + c
    const int b = i >> 9;
    const int c = i & 511;
    const float* p = part + (size_t)b * 4 * C_DIM + c;
    out[i] = (p[0] + p[512]) + (p[1024] + p[1536]);
}

extern "C" void kernel_launch(void* const* d_in, const int* in_sizes, int n_in,
                              void* d_out, int out_size, void* d_ws, size_t ws_size,
                              hipStream_t stream) {
    const float* x = (const float*)d_in[0];       // (128,28,28,512) fp32
    const float* anchors = (const float*)d_in[1]; // (64,512) fp32
    float* out = (float*)d_out;                   // (128,512) fp32

    unsigned short* an_h = (unsigned short*)d_ws;                 // 64*512 ushort
    unsigned short* an_l = an_h + (size_t)K_DIM * C_DIM;          // 64*512 ushort
    float* Tc = (float*)(an_l + (size_t)K_DIM * C_DIM);           // 128*784 fp32
    float* part = Tc + (size_t)B_DIM * N_PIX;                     // 512*512 fp32

    anchors_norm_kernel<<<K_DIM, 64, 0, stream>>>(anchors, an_h, an_l);
    cost_t_kernel<<<M_ROWS / MT, 256, 0, stream>>>(x, an_h, an_l, Tc);
    sinkhorn_kernel<<<B_DIM, 256, 0, stream>>>(Tc);
    pool_partial<<<B_DIM * 4, 256, 0, stream>>>(x, Tc, part);
    pool_reduce<<<B_DIM * C_DIM / 256, 256, 0, stream>>>(part, out);
}